// Round 15
// baseline (175.034 us; speedup 1.0000x reference)
//
#include <hip/hip_runtime.h>
#include <math.h>

// Problem constants
#define BATCH 4
#define CIN   256
#define CCH   128      // Cout
#define HW    4096     // 64*64
#define CQK   16

using short8   = __attribute__((ext_vector_type(8))) short;
using floatx4  = __attribute__((ext_vector_type(4))) float;
using floatx16 = __attribute__((ext_vector_type(16))) float;
using uint4v   = __attribute__((ext_vector_type(4))) unsigned int;

// tanh via raw intrinsics: 1 v_mul + v_exp + v_add + v_rcp + v_fma.
// Saturates correctly: x->+inf => exp2->inf => rcp->0 => 1; x->-inf => -1.
__device__ __forceinline__ float fast_tanh(float x) {
    float e = __builtin_amdgcn_exp2f(x * 2.8853900817779268f);  // e^{2x}
    float r = __builtin_amdgcn_rcpf(e + 1.0f);
    return __builtin_fmaf(-2.0f, r, 1.0f);
}

__device__ __forceinline__ unsigned short f2bf(float f) {
    unsigned u = __float_as_uint(f);
    u += 0x7fff + ((u >> 16) & 1);   // RNE
    return (unsigned short)(u >> 16);
}

__device__ __forceinline__ float bf2f(unsigned short u) {
    return __uint_as_float(((unsigned)u) << 16);
}

// C/D row map for mfma_f32_32x32x16: row = (r&3) + 8*(r>>2) + 4*hi, col = lane&31
#define ROWMAP(r, hi) (((r) & 3) + (((r) >> 2) << 3) + ((hi) << 2))

#define XTP_ROW   (66 * 256)          // shorts per padded row
#define XTP_BATCH (66 * 66 * 256)     // shorts per batch

// ---------------------------------------------------------------------------
// 1) prep_all: [0,1024) x-transpose+halo; [1024,2176) conv weights;
//    [2176,2256) qkv weights; [2256] zero stats. grid 2257, block 256.
// ---------------------------------------------------------------------------
__global__ __launch_bounds__(256) void prep_all_kernel(
        const float* __restrict__ x, const float* __restrict__ w,
        const float* __restrict__ qw, const float* __restrict__ qb,
        const float* __restrict__ kw, const float* __restrict__ kb,
        const float* __restrict__ vw, const float* __restrict__ vb,
        unsigned short* __restrict__ xTp, unsigned short* __restrict__ Wb2,
        unsigned short* __restrict__ Wqkv, float* __restrict__ biasAll,
        float* __restrict__ statsS, float* __restrict__ statsQ) {
    const int bx = blockIdx.x, tid = threadIdx.x;
    if (bx < 1024) {
        __shared__ unsigned short lds[64][72];
        const int ci0 = (bx & 3) << 6, yr = (bx >> 2) & 63, b = bx >> 8;
        const int cir = tid >> 2, xc = tid & 3;
        const float* xp = x + (((b << 8) + ci0 + cir) << 12) + (yr << 6) + xc * 16;
#pragma unroll
        for (int j = 0; j < 4; ++j) {
            float4 v = *(const float4*)(xp + j * 4);
            int xi = xc * 16 + j * 4;
            lds[xi + 0][cir] = f2bf(v.x);
            lds[xi + 1][cir] = f2bf(v.y);
            lds[xi + 2][cir] = f2bf(v.z);
            lds[xi + 3][cir] = f2bf(v.w);
        }
        const short8 z8 = (short8){0,0,0,0,0,0,0,0};
        if (tid < 16) {
            int col = (tid >> 3) ? 65 : 0;
            int part = tid & 7;
            *(short8*)(xTp + b * XTP_BATCH + (yr + 1) * XTP_ROW + col * 256 +
                       ci0 + part * 8) = z8;
        }
        if (yr == 0 || yr == 63) {
            int row = (yr == 0) ? 0 : 65;
            for (int e = tid; e < 528; e += 256) {
                int xi = e >> 3, part = e & 7;
                *(short8*)(xTp + b * XTP_BATCH + row * XTP_ROW + xi * 256 +
                           ci0 + part * 8) = z8;
            }
        }
        __syncthreads();
        const int xr = tid >> 2, part = tid & 3;
        unsigned short* dst = xTp + b * XTP_BATCH + (yr + 1) * XTP_ROW +
                              (xr + 1) * 256 + ci0 + part * 16;
        *(short8*)(dst + 0) = *(const short8*)&lds[xr][part * 16 + 0];
        *(short8*)(dst + 8) = *(const short8*)&lds[xr][part * 16 + 8];
    } else if (bx < 2176) {
        int o = (bx - 1024) * 256 + tid;                 // < 294912
        int s   = o & 31;
        int co  = (o >> 5) & 127;
        int cc  = (o >> 12) & 7;
        int tap = o >> 15;
        int ci  = (cc << 5) + s;
        Wb2[o] = f2bf(w[co * 2304 + ci * 9 + tap]);
    } else if (bx < 2256) {
        int idx = (bx - 2176) * 256 + tid;               // < 20480
        int o = idx >> 7, c = idx & 127;
        float wv = (o < 16) ? qw[(o << 7) + c]
                 : (o < 32) ? kw[((o - 16) << 7) + c]
                            : vw[((o - 32) << 7) + c];
        Wqkv[idx] = f2bf(wv);
        if (idx < 160)
            biasAll[idx] = (idx < 16) ? qb[idx] : (idx < 32) ? kb[idx - 16] : vb[idx - 32];
    } else {
        if (tid < 128) { statsS[tid] = 0.f; statsQ[tid] = 0.f; }
    }
}

// ---------------------------------------------------------------------------
// 2) Conv implicit GEMM, m97-style (unchanged -- atomic-free BN partials).
// ---------------------------------------------------------------------------
#define LOADBAND(R, KY)                                                        \
    {                                                                          \
        const unsigned short* g_ = bandbase + (KY) * XTP_ROW;                  \
        _Pragma("unroll")                                                      \
        for (int j = 0; j < 4; ++j)                                            \
            R[j] = *(const short8*)(g_ + ((tid + j * 256) << 3));              \
        if (tid < 64) R[4] = *(const short8*)(g_ + ((1024 + tid) << 3));       \
    }

#define WRITEBAND(R, BUF)                                                      \
    {                                                                          \
        char* p_ = (char*)&Bl[BUF][0];                                         \
        _Pragma("unroll")                                                      \
        for (int j = 0; j < 4; ++j) {                                          \
            int bb_ = (tid + j * 256) << 4;                                    \
            *(short8*)(p_ + (bb_ ^ (((bb_ >> 9) & 7) << 4))) = R[j];           \
        }                                                                      \
        if (tid < 64) {                                                        \
            int bb_ = (1024 + tid) << 4;                                       \
            *(short8*)(p_ + (bb_ ^ (((bb_ >> 9) & 7) << 4))) = R[4];           \
        }                                                                      \
    }

#define LOADA(P, TAP)                                                          \
    {                                                                          \
        const unsigned short* ar_ = Wb2 + ((TAP) << 15) + (aco0 << 5) + (quad << 3); \
        _Pragma("unroll")                                                      \
        for (int cc = 0; cc < 8; ++cc) {                                       \
            P[2 * cc]     = *(const short8*)(ar_ + (cc << 12));                \
            P[2 * cc + 1] = *(const short8*)(ar_ + (cc << 12) + 512);          \
        }                                                                      \
    }

#define CONVSTEP(BUF, KX, PC, PN, TAPN, PREF)                                  \
    {                                                                          \
        const char* bp_ = (const char*)&Bl[BUF][0];                            \
        const int pl0_ = l15 + (KX);                                           \
        const int sw_ = (pl0_ & 7) << 4;                                       \
        const int b0_ = (pl0_ << 9) + (quad << 4);                             \
        const int b1_ = b0_ + (16 << 9);                                       \
        const unsigned short* arn_ = Wb2 + ((TAPN) << 15) + (aco0 << 5) + (quad << 3); \
        _Pragma("unroll")                                                      \
        for (int cc = 0; cc < 8; ++cc) {                                       \
            if (PREF) {                                                        \
                PN[2 * cc]     = *(const short8*)(arn_ + (cc << 12));          \
                PN[2 * cc + 1] = *(const short8*)(arn_ + (cc << 12) + 512);    \
            }                                                                  \
            short8 bf0 = *(const short8*)(bp_ + ((b0_ + (cc << 6)) ^ sw_));    \
            short8 bf1 = *(const short8*)(bp_ + ((b1_ + (cc << 6)) ^ sw_));    \
            acc00 = __builtin_amdgcn_mfma_f32_16x16x32_bf16(PC[2 * cc], bf0, acc00, 0, 0, 0); \
            acc01 = __builtin_amdgcn_mfma_f32_16x16x32_bf16(PC[2 * cc], bf1, acc01, 0, 0, 0); \
            acc10 = __builtin_amdgcn_mfma_f32_16x16x32_bf16(PC[2 * cc + 1], bf0, acc10, 0, 0, 0); \
            acc11 = __builtin_amdgcn_mfma_f32_16x16x32_bf16(PC[2 * cc + 1], bf1, acc11, 0, 0, 0); \
        }                                                                      \
    }

__global__ __launch_bounds__(256, 2) void conv_mfma_kernel(
        const unsigned short* __restrict__ xTp, const unsigned short* __restrict__ Wb2,
        float* __restrict__ y, float* __restrict__ convP) {
    const int tid = threadIdx.x;
    const int w = tid >> 6, lane = tid & 63, l15 = lane & 15, quad = lane >> 4;
    const int idx = blockIdx.x;
    const int xcd = idx & 7, rr = idx >> 3;
    const int yl = rr & 7, ph = (rr >> 3) & 1, b = rr >> 4;
    const int yr = (xcd << 3) + yl;
    const int cobase = w << 5;
    const int px0 = ph << 5;
    const int aco0 = cobase + l15;

    __shared__ __align__(16) unsigned short Bl[2][8704];

    const unsigned short* bandbase = xTp + b * XTP_BATCH + yr * XTP_ROW + (px0 << 8);

    floatx4 acc00 = (floatx4){0.f, 0.f, 0.f, 0.f};
    floatx4 acc01 = (floatx4){0.f, 0.f, 0.f, 0.f};
    floatx4 acc10 = (floatx4){0.f, 0.f, 0.f, 0.f};
    floatx4 acc11 = (floatx4){0.f, 0.f, 0.f, 0.f};

    short8 r0[5], r1[5], r2[5];
    short8 AbA[16], AbB[16];

    LOADBAND(r0, 0);
    WRITEBAND(r0, 0);
    LOADBAND(r1, 1);
    LOADA(AbA, 0);
    __syncthreads();

    WRITEBAND(r1, 1);
    LOADBAND(r2, 2);
    CONVSTEP(0, 0, AbA, AbB, 1, 1)
    CONVSTEP(0, 1, AbB, AbA, 2, 1)
    CONVSTEP(0, 2, AbA, AbB, 3, 1)
    __syncthreads();

    WRITEBAND(r2, 0);
    CONVSTEP(1, 0, AbB, AbA, 4, 1)
    CONVSTEP(1, 1, AbA, AbB, 5, 1)
    CONVSTEP(1, 2, AbB, AbA, 6, 1)
    __syncthreads();

    CONVSTEP(0, 0, AbA, AbB, 7, 1)
    CONVSTEP(0, 1, AbB, AbA, 8, 1)
    CONVSTEP(0, 2, AbA, AbB, 0, 0)

#pragma unroll
    for (int ns = 0; ns < 2; ++ns) {
        int px = px0 + (ns << 4) + l15;
        floatx4 a0 = ns ? acc01 : acc00;
        floatx4 a1 = ns ? acc11 : acc10;
#pragma unroll
        for (int r = 0; r < 4; ++r) {
            int co0 = cobase + (quad << 2) + r;
            y[(((b << 7) + co0) << 12) + (yr << 6) + px] = a0[r];
            y[(((b << 7) + co0 + 16) << 12) + (yr << 6) + px] = a1[r];
        }
    }

#pragma unroll
    for (int ms = 0; ms < 2; ++ms) {
        floatx4 aa = ms ? acc10 : acc00;
        floatx4 ab = ms ? acc11 : acc01;
#pragma unroll
        for (int r = 0; r < 4; ++r) {
            float s = aa[r] + ab[r];
            float q = aa[r] * aa[r] + ab[r] * ab[r];
#pragma unroll
            for (int off = 1; off < 16; off <<= 1) {
                s += __shfl_xor(s, off);
                q += __shfl_xor(q, off);
            }
            if (l15 == 0) {
                int co = cobase + ms * 16 + (quad << 2) + r;
                convP[(co << 9) + idx] = s;
                convP[((128 + co) << 9) + idx] = q;
            }
        }
    }
}

// ---------------------------------------------------------------------------
// 2b) stats_reduce: sum the 512 per-block partials per slot.
//     grid 256 (slot = co for S, 128+co for Q), block 64.
// ---------------------------------------------------------------------------
__global__ __launch_bounds__(64) void stats_reduce_kernel(
        const float* __restrict__ convP, float* __restrict__ statsS,
        float* __restrict__ statsQ) {
    const int s = blockIdx.x, t = threadIdx.x;
    const float* p = convP + (s << 9);
    float v = 0.f;
#pragma unroll
    for (int j = 0; j < 8; ++j) v += p[t + (j << 6)];
#pragma unroll
    for (int off = 32; off; off >>= 1) v += __shfl_xor(v, off);
    if (t == 0) {
        if (s < 128) statsS[s] = v;
        else         statsQ[s - 128] = v;
    }
}

// ---------------------------------------------------------------------------
// 3) BN apply + ReLU (scale computed inline from sums) -> featB + fT.
// grid(2, 64, 4), block 256
// ---------------------------------------------------------------------------
__global__ __launch_bounds__(256) void bn_apply_kernel(
        const float* __restrict__ y, const float* __restrict__ statsS,
        const float* __restrict__ statsQ, const float* __restrict__ gamma,
        const float* __restrict__ beta, unsigned short* __restrict__ featB,
        unsigned short* __restrict__ fT) {
    __shared__ unsigned short lds[64][72];
    const int tid = threadIdx.x;
    const int c0 = blockIdx.x * 64, n0 = blockIdx.y * 64, b = blockIdx.z;
    const int cir = tid >> 2, xc = tid & 3;
    const int c = c0 + cir;
    const float S = statsS[c], Q = statsQ[c];
    const float mean = S * (1.f / 16384.f);
    const float var  = Q * (1.f / 16384.f) - mean * mean;
    const float rstd = rsqrtf(var + 1e-5f);
    const float sc = gamma[c] * rstd;
    const float sh = beta[c] - mean * sc;
    const float* yp = y + (((b << 7) + c) << 12) + n0 + xc * 16;
    unsigned short* fp = featB + (((b << 7) + c) << 12) + n0 + xc * 16;
#pragma unroll
    for (int j = 0; j < 4; ++j) {
        float4 v = *(const float4*)(yp + j * 4);
        ushort4 o;
        o.x = f2bf(fmaxf(fmaf(v.x, sc, sh), 0.f));
        o.y = f2bf(fmaxf(fmaf(v.y, sc, sh), 0.f));
        o.z = f2bf(fmaxf(fmaf(v.z, sc, sh), 0.f));
        o.w = f2bf(fmaxf(fmaf(v.w, sc, sh), 0.f));
        *(ushort4*)(fp + j * 4) = o;
        int ni = xc * 16 + j * 4;
        lds[ni + 0][cir] = o.x;
        lds[ni + 1][cir] = o.y;
        lds[ni + 2][cir] = o.z;
        lds[ni + 3][cir] = o.w;
    }
    __syncthreads();
    const int nr = tid >> 2, part = tid & 3;
    unsigned short* dst = fT + (((b << 12) + n0 + nr) << 7) + c0 + part * 16;
    *(short8*)(dst + 0) = *(const short8*)&lds[nr][part * 16 + 0];
    *(short8*)(dst + 8) = *(const short8*)&lds[nr][part * 16 + 8];
}

// ---------------------------------------------------------------------------
// 4) Fused cam_energy (blocks [0,256)) + qkv (blocks [256,512)). grid 512.
// ---------------------------------------------------------------------------
__global__ __launch_bounds__(256) void camqkv_kernel(
        const unsigned short* __restrict__ featB, float* __restrict__ ep,
        const unsigned short* __restrict__ Wqkv, const float* __restrict__ biasAll,
        const unsigned short* __restrict__ fT,
        unsigned short* __restrict__ qT, unsigned short* __restrict__ kT,
        unsigned short* __restrict__ vB) {
    const int bx = blockIdx.x, tid = threadIdx.x;
    const int l31 = tid & 31, hi = (tid >> 5) & 1;
    if (bx < 256) {
        // cam_energy: split-K 64, kc = bx&63, b = bx>>6
        const int kc = bx & 63, b = bx >> 6, wv = tid >> 6;
        floatx16 acc[4];
#pragma unroll
        for (int t = 0; t < 4; ++t)
#pragma unroll
            for (int r = 0; r < 16; ++r) acc[t][r] = 0.f;
        for (int s = 0; s < 4; ++s) {
            const int k0 = (kc << 6) + (s << 4) + (hi << 3);
            short8 fr = *(const short8*)&featB[(((b << 7) + (wv << 5) + l31) << 12) + k0];
            short8 fc0 = *(const short8*)&featB[(((b << 7) +  0 + l31) << 12) + k0];
            short8 fc1 = *(const short8*)&featB[(((b << 7) + 32 + l31) << 12) + k0];
            short8 fc2 = *(const short8*)&featB[(((b << 7) + 64 + l31) << 12) + k0];
            short8 fc3 = *(const short8*)&featB[(((b << 7) + 96 + l31) << 12) + k0];
            acc[0] = __builtin_amdgcn_mfma_f32_32x32x16_bf16(fr, fc0, acc[0], 0, 0, 0);
            acc[1] = __builtin_amdgcn_mfma_f32_32x32x16_bf16(fr, fc1, acc[1], 0, 0, 0);
            acc[2] = __builtin_amdgcn_mfma_f32_32x32x16_bf16(fr, fc2, acc[2], 0, 0, 0);
            acc[3] = __builtin_amdgcn_mfma_f32_32x32x16_bf16(fr, fc3, acc[3], 0, 0, 0);
        }
#pragma unroll
        for (int t = 0; t < 4; ++t)
#pragma unroll
            for (int r = 0; r < 16; ++r) {
                int c = ((tid >> 6) << 5) + ROWMAP(r, hi);
                int d = (t << 5) + l31;
                ep[(((kc << 2) + b) << 14) + (c << 7) + d] = acc[t][r];
            }
    } else {
        // qkv: bi = bx-256; ntile = bi&63, b = bi>>6
        const int bi = bx - 256, b = bi >> 6, w = tid >> 6;
        const int n0 = ((bi & 63) << 6) + ((w >> 1) << 5);
        const int tstart = (w & 1) ? 3 : 0;
        const int tcnt   = (w & 1) ? 2 : 3;
        floatx16 acc[3];
#pragma unroll
        for (int t = 0; t < 3; ++t)
#pragma unroll
            for (int r = 0; r < 16; ++r) acc[t][r] = 0.f;
        for (int s = 0; s < 8; ++s) {
            const int k0 = (s << 4) + (hi << 3);
            short8 bf = *(const short8*)&fT[(((b << 12) + n0 + l31) << 7) + k0];
#pragma unroll
            for (int ti = 0; ti < 3; ++ti) {
                if (ti < tcnt) {
                    short8 aw = *(const short8*)&Wqkv[((((tstart + ti) << 5) + l31) << 7) + k0];
                    acc[ti] = __builtin_amdgcn_mfma_f32_32x32x16_bf16(aw, bf, acc[ti], 0, 0, 0);
                }
            }
        }
        const int n = n0 + l31;
#pragma unroll
        for (int ti = 0; ti < 3; ++ti) {
            if (ti >= tcnt) continue;
            const int t = tstart + ti;
#pragma unroll
            for (int r = 0; r < 16; ++r) {
                int o = (t << 5) + ROWMAP(r, hi);
                float val = acc[ti][r] + biasAll[o];
                if (t == 0) {
                    if (o < 16) qT[(((b << 12) + n) << 4) + o] = f2bf(val);
                    else        kT[(((b << 12) + n) << 4) + o - 16] = f2bf(val);
                } else if (o >= 32) {
                    vB[(((b << 7) + o - 32) << 12) + n] = f2bf(val);
                }
            }
        }
    }
}

// ---------------------------------------------------------------------------
// 5) Fused pam (blocks [0,512)) + cam_attn (blocks [512,768)). grid 768.
//    ROUND-15: barrier-halving with ALL validated invariants intact.
//    Each double-buffer now holds TWO aligned 32-col tiles (per-tile
//    stride 40 = 80B rows -> single ds_read_b128; r10 alignment rule).
//    One barrier pair covers both tiles: barriers 32 -> 16 per block.
//    Step order: tile-A V-loads EARLY -> QK_A -> K prefetch -> tile-B
//    V-loads (latency hidden under tanh_A + PV_A) -> tanh_A -> permlane
//    (r14-validated wiring) -> QK_B (covered by PV_A) -> PV_A -> tanh_B
//    -> PV_B. r9's 64-col failure was confounded (misaligned stride +
//    late loads); this is the clean test.
// ---------------------------------------------------------------------------
#define PAM_STEP2(LB, NC0)                                                        \
    {                                                                             \
        const unsigned short* lbA_ = (LB);                                        \
        const unsigned short* lbB_ = (LB) + 5120;                                 \
        short8 aAl0 = *(const short8*)(lbA_ + ( l31       * 40) + hi * 8);        \
        short8 aAh0 = *(const short8*)(lbA_ + ( l31       * 40) + 16 + hi * 8);   \
        short8 aAl1 = *(const short8*)(lbA_ + ((32 + l31) * 40) + hi * 8);        \
        short8 aAh1 = *(const short8*)(lbA_ + ((32 + l31) * 40) + 16 + hi * 8);   \
        short8 aAl2 = *(const short8*)(lbA_ + ((64 + l31) * 40) + hi * 8);        \
        short8 aAh2 = *(const short8*)(lbA_ + ((64 + l31) * 40) + 16 + hi * 8);   \
        short8 aAl3 = *(const short8*)(lbA_ + ((96 + l31) * 40) + hi * 8);        \
        short8 aAh3 = *(const short8*)(lbA_ + ((96 + l31) * 40) + 16 + hi * 8);   \
        floatx16 sA_ = __builtin_amdgcn_mfma_f32_32x32x16_bf16(ak, bq, zero16, 0, 0, 0); \
        ak = *(const short8*)&kT[(((b << 12) + nbase + (((NC0) + 1) << 5) + l31) << 4) + hi * 8]; \
        short8 aBl0 = *(const short8*)(lbB_ + ( l31       * 40) + hi * 8);        \
        short8 aBh0 = *(const short8*)(lbB_ + ( l31       * 40) + 16 + hi * 8);   \
        short8 aBl1 = *(const short8*)(lbB_ + ((32 + l31) * 40) + hi * 8);        \
        short8 aBh1 = *(const short8*)(lbB_ + ((32 + l31) * 40) + 16 + hi * 8);   \
        short8 aBl2 = *(const short8*)(lbB_ + ((64 + l31) * 40) + hi * 8);        \
        short8 aBh2 = *(const short8*)(lbB_ + ((64 + l31) * 40) + 16 + hi * 8);   \
        short8 aBl3 = *(const short8*)(lbB_ + ((96 + l31) * 40) + hi * 8);        \
        short8 aBh3 = *(const short8*)(lbB_ + ((96 + l31) * 40) + 16 + hi * 8);   \
        unsigned pA_[8];                                                          \
        _Pragma("unroll")                                                         \
        for (int i = 0; i < 8; ++i) {                                             \
            float t0 = fast_tanh(sA_[2 * i]);                                     \
            float t1 = fast_tanh(sA_[2 * i + 1]);                                 \
            pA_[i] = (__float_as_uint(t1) & 0xFFFF0000u) | (__float_as_uint(t0) >> 16); \
        }                                                                         \
        unsigned a0 = pA_[0], a1 = pA_[1], a2 = pA_[2], a3 = pA_[3];              \
        unsigned a4 = pA_[4], a5 = pA_[5], a6 = pA_[6], a7 = pA_[7];              \
        asm("v_permlane32_swap_b32 %0, %1" : "+v"(a0), "+v"(a2));                 \
        asm("v_permlane32_swap_b32 %0, %1" : "+v"(a1), "+v"(a3));                 \
        asm("v_permlane32_swap_b32 %0, %1" : "+v"(a4), "+v"(a6));                 \
        asm("v_permlane32_swap_b32 %0, %1" : "+v"(a5), "+v"(a7));                 \
        uint4v b1uA, b2uA;                                                        \
        b1uA[0] = a0; b1uA[1] = a1; b1uA[2] = a2; b1uA[3] = a3;                   \
        b2uA[0] = a4; b2uA[1] = a5; b2uA[2] = a6; b2uA[3] = a7;                   \
        short8 B1A = __builtin_bit_cast(short8, b1uA);                            \
        short8 B2A = __builtin_bit_cast(short8, b2uA);                            \
        floatx16 sB_ = __builtin_amdgcn_mfma_f32_32x32x16_bf16(ak, bq, zero16, 0, 0, 0); \
        if ((NC0) + 2 < 32)                                                       \
            ak = *(const short8*)&kT[(((b << 12) + nbase + (((NC0) + 2) << 5) + l31) << 4) + hi * 8]; \
        __builtin_amdgcn_s_setprio(1);                                            \
        acc[0] = __builtin_amdgcn_mfma_f32_32x32x16_bf16(aAl0, B1A, acc[0], 0, 0, 0); \
        acc[0] = __builtin_amdgcn_mfma_f32_32x32x16_bf16(aAh0, B2A, acc[0], 0, 0, 0); \
        acc[1] = __builtin_amdgcn_mfma_f32_32x32x16_bf16(aAl1, B1A, acc[1], 0, 0, 0); \
        acc[1] = __builtin_amdgcn_mfma_f32_32x32x16_bf16(aAh1, B2A, acc[1], 0, 0, 0); \
        acc[2] = __builtin_amdgcn_mfma_f32_32x32x16_bf16(aAl2, B1A, acc[2], 0, 0, 0); \
        acc[2] = __builtin_amdgcn_mfma_f32_32x32x16_bf16(aAh2, B2A, acc[2], 0, 0, 0); \
        acc[3] = __builtin_amdgcn_mfma_f32_32x32x16_bf16(aAl3, B1A, acc[3], 0, 0, 0); \
        acc[3] = __builtin_amdgcn_mfma_f32_32x32x16_bf16(aAh3, B2A, acc[3], 0, 0, 0); \
        __builtin_amdgcn_s_setprio(0);                                            \
        unsigned pB_[8];                                                          \
        _Pragma("unroll")                                                         \
        for (int i = 0; i < 8; ++i) {                                             \
            float t0 = fast_tanh(sB_[2 * i]);                                     \
            float t1 = fast_tanh(sB_[2 * i + 1]);                                 \
            pB_[i] = (__float_as_uint(t1) & 0xFFFF0000u) | (__float_as_uint(t0) >> 16); \
        }                                                                         \
        unsigned c0_ = pB_[0], c1_ = pB_[1], c2_ = pB_[2], c3_ = pB_[3];          \
        unsigned c4_ = pB_[4], c5_ = pB_[5], c6_ = pB_[6], c7_ = pB_[7];          \
        asm("v_permlane32_swap_b32 %0, %1" : "+v"(c0_), "+v"(c2_));               \
        asm("v_permlane32_swap_b32 %0, %1" : "+v"(c1_), "+v"(c3_));               \
        asm("v_permlane32_swap_b32 %0, %1" : "+v"(c4_), "+v"(c6_));               \
        asm("v_permlane32_swap_b32 %0, %1" : "+v"(c5_), "+v"(c7_));               \
        uint4v b1uB, b2uB;                                                        \
        b1uB[0] = c0_; b1uB[1] = c1_; b1uB[2] = c2_; b1uB[3] = c3_;               \
        b2uB[0] = c4_; b2uB[1] = c5_; b2uB[2] = c6_; b2uB[3] = c7_;               \
        short8 B1B = __builtin_bit_cast(short8, b1uB);                            \
        short8 B2B = __builtin_bit_cast(short8, b2uB);                            \
        __builtin_amdgcn_s_setprio(1);                                            \
        acc[0] = __builtin_amdgcn_mfma_f32_32x32x16_bf16(aBl0, B1B, acc[0], 0, 0, 0); \
        acc[0] = __builtin_amdgcn_mfma_f32_32x32x16_bf16(aBh0, B2B, acc[0], 0, 0, 0); \
        acc[1] = __builtin_amdgcn_mfma_f32_32x32x16_bf16(aBl1, B1B, acc[1], 0, 0, 0); \
        acc[1] = __builtin_amdgcn_mfma_f32_32x32x16_bf16(aBh1, B2B, acc[1], 0, 0, 0); \
        acc[2] = __builtin_amdgcn_mfma_f32_32x32x16_bf16(aBl2, B1B, acc[2], 0, 0, 0); \
        acc[2] = __builtin_amdgcn_mfma_f32_32x32x16_bf16(aBh2, B2B, acc[2], 0, 0, 0); \
        acc[3] = __builtin_amdgcn_mfma_f32_32x32x16_bf16(aBl3, B1B, acc[3], 0, 0, 0); \
        acc[3] = __builtin_amdgcn_mfma_f32_32x32x16_bf16(aBh3, B2B, acc[3], 0, 0, 0); \
        __builtin_amdgcn_s_setprio(0);                                            \
    }

__global__ __launch_bounds__(256) void pam_attn_kernel(
        const unsigned short* __restrict__ qT, const unsigned short* __restrict__ kT,
        const unsigned short* __restrict__ vB, unsigned short* __restrict__ pamP,
        const float* __restrict__ ep, unsigned short* __restrict__ attnB) {
    const int bx = blockIdx.x, tid = threadIdx.x;
    if (bx < 512) {
        const int nh = bx & 3, b = bx >> 7;
        const int w = tid >> 6, lane = tid & 63, l31 = lane & 31, hi = lane >> 5;
        const int m0 = (((bx >> 2) & 31) << 7) + (w << 5);

        // 2 buffers x 2 tiles x 128 rows x 40 shorts = 40,960 B
        __shared__ __align__(16) unsigned short vtile[2][10240];

        short8 bq = *(const short8*)&qT[(((b << 12) + m0 + l31) << 4) + hi * 8];

        floatx16 acc[4], zero16;
#pragma unroll
        for (int r = 0; r < 16; ++r) {
            acc[0][r] = 0.f; acc[1][r] = 0.f; acc[2][r] = 0.f; acc[3][r] = 0.f;
            zero16[r] = 0.f;
        }

        const int nbase = nh << 10;

        // staging mapping: thread -> (row 0..127, 32B half); 2 tiles/buffer
        const int srow = tid >> 1, shalf = tid & 1;
        const unsigned short* vg = vB + (((b << 7) + srow) << 12) + nbase + shalf * 16;
        unsigned short* sw0t0 = &vtile[0][srow * 40 + shalf * 16];
        unsigned short* sw0t1 = &vtile[0][5120 + srow * 40 + shalf * 16];
        unsigned short* sw1t0 = &vtile[1][srow * 40 + shalf * 16];
        unsigned short* sw1t1 = &vtile[1][5120 + srow * 40 + shalf * 16];

        short8 ak = *(const short8*)&kT[(((b << 12) + nbase + l31) << 4) + hi * 8];

        // prologue: fetch pairs 0 (tiles 0,1) and 1 (tiles 2,3); write pair 0
        short8 gA0 = *(const short8*)(vg + 0);
        short8 gA1 = *(const short8*)(vg + 8);
        short8 gA2 = *(const short8*)(vg + 32);
        short8 gA3 = *(const short8*)(vg + 40);
        short8 gB0 = *(const short8*)(vg + 64);
        short8 gB1 = *(const short8*)(vg + 72);
        short8 gB2 = *(const short8*)(vg + 96);
        short8 gB3 = *(const short8*)(vg + 104);
        *(short8*)(sw0t0 + 0) = gA0;
        *(short8*)(sw0t0 + 8) = gA1;
        *(short8*)(sw0t1 + 0) = gA2;
        *(short8*)(sw0t1 + 8) = gA3;

        for (int t = 0; t < 8; ++t) {
            const int e0 = t << 2;   // first tile of phase A
            // ---- phase A: consume tiles e0, e0+1 from buf0 ----
            __syncthreads();
            *(short8*)(sw1t0 + 0) = gB0;        // tiles e0+2, e0+3 -> buf1
            *(short8*)(sw1t0 + 8) = gB1;
            *(short8*)(sw1t1 + 0) = gB2;
            *(short8*)(sw1t1 + 8) = gB3;
            if (t < 7) {                         // fetch tiles e0+4, e0+5
                gA0 = *(const short8*)(vg + (e0 + 4) * 32);
                gA1 = *(const short8*)(vg + (e0 + 4) * 32 + 8);
                gA2 = *(const short8*)(vg + (e0 + 5) * 32);
                gA3 = *(const short8*)(vg + (e0 + 5) * 32 + 8);
            }
            PAM_STEP2(&vtile[0][0], e0);
            // ---- phase B: consume tiles e0+2, e0+3 from buf1 ----
            __syncthreads();
            if (t < 7) {
                *(short8*)(sw0t0 + 0) = gA0;    // tiles e0+4, e0+5 -> buf0
                *(short8*)(sw0t0 + 8) = gA1;
                *(short8*)(sw0t1 + 0) = gA2;
                *(short8*)(sw0t1 + 8) = gA3;
                gB0 = *(const short8*)(vg + (e0 + 6) * 32);  // tiles e0+6, e0+7
                gB1 = *(const short8*)(vg + (e0 + 6) * 32 + 8);
                gB2 = *(const short8*)(vg + (e0 + 7) * 32);
                gB3 = *(const short8*)(vg + (e0 + 7) * 32 + 8);
            }
            PAM_STEP2(&vtile[1][0], e0 + 2);
        }

        const int pbase = (((nh << 2) + b) << 19) + m0 + l31;
#pragma unroll
        for (int ct = 0; ct < 4; ++ct)
#pragma unroll
            for (int r = 0; r < 16; ++r) {
                int c = (ct << 5) + ROWMAP(r, hi);
                pamP[pbase + (c << 12)] = f2bf(acc[ct][r]);
            }
    } else {
        // cam_attn: bi = bx-512 (0..255): b = bi>>6, 2 rows per block
        const int bi = bx - 512, b = bi >> 6;
        const int half = tid >> 7, t = tid & 127;
        const int c = ((bi & 63) << 1) + half;
        float v = 0.f;
#pragma unroll 8
        for (int s = 0; s < 64; ++s)
            v += ep[(((s << 2) + b) << 14) + (c << 7) + t];
        float m = v;
        for (int off = 32; off; off >>= 1) m = fmaxf(m, __shfl_down(m, off));
        __shared__ float mx[4];
        if ((tid & 63) == 0) mx[tid >> 6] = m;
        __syncthreads();
        float M = fmaxf(mx[half << 1], mx[(half << 1) + 1]);
        attnB[(b << 14) + (c << 7) + t] = f2bf(fast_tanh(M - v));
    }
}

// ---------------------------------------------------------------------------
// 6) Combine: out = 3*feat + g_ca*(attn @ f) + g_pa*(sum_4 pamP).
// grid(64, 4), block 256.
// ---------------------------------------------------------------------------
__global__ __launch_bounds__(256) void combine_kernel(
        const unsigned short* __restrict__ attnB, const unsigned short* __restrict__ fT,
        const unsigned short* __restrict__ featB, const unsigned short* __restrict__ pamP,
        const float* __restrict__ gca, const float* __restrict__ gpa,
        float* __restrict__ out) {
    const int b = blockIdx.y, tid = threadIdx.x;
    const int w = tid >> 6, l31 = tid & 31, hi = (tid >> 5) & 1;
    const int m0 = (blockIdx.x << 6) + ((w >> 1) << 5);
    const int ct0 = (w & 1) << 1;
    floatx16 acc[2];
#pragma unroll
    for (int t = 0; t < 2; ++t)
#pragma unroll
        for (int r = 0; r < 16; ++r) acc[t][r] = 0.f;

    for (int s = 0; s < 8; ++s) {
        const int k0 = (s << 4) + (hi << 3);
        short8 bf = *(const short8*)&fT[(((b << 12) + m0 + l31) << 7) + k0];
        short8 a0 = *(const short8*)&attnB[(b << 14) + ((((ct0 + 0) << 5) + l31) << 7) + k0];
        short8 a1 = *(const short8*)&attnB[(b << 14) + ((((ct0 + 1) << 5) + l31) << 7) + k0];
        acc[0] = __builtin_amdgcn_mfma_f32_32x32x16_bf16(a0, bf, acc[0], 0, 0, 0);
        acc[1] = __builtin_amdgcn_mfma_f32_32x32x16_bf16(a1, bf, acc[1], 0, 0, 0);
    }
    const float gc = gca[0], gp = gpa[0];
    const int m = m0 + l31;
#pragma unroll
    for (int t = 0; t < 2; ++t)
#pragma unroll
        for (int r = 0; r < 16; ++r) {
            int c = ((ct0 + t) << 5) + ROWMAP(r, hi);
            int ci = (c << 12) + m;
            float p = bf2f(pamP[((0 * 4 + b) << 19) + ci]) +
                      bf2f(pamP[((1 * 4 + b) << 19) + ci]) +
                      bf2f(pamP[((2 * 4 + b) << 19) + ci]) +
                      bf2f(pamP[((3 * 4 + b) << 19) + ci]);
            float fb = bf2f(featB[(((b << 7) + c) << 12) + m]);
            out[(((b << 7) + c) << 12) + m] = 3.f * fb + gc * acc[t][r] + gp * p;
        }
}

// ---------------------------------------------------------------------------
extern "C" void kernel_launch(void* const* d_in, const int* in_sizes, int n_in,
                              void* d_out, int out_size, void* d_ws, size_t ws_size,
                              hipStream_t stream) {
    const float* x      = (const float*)d_in[0];
    const float* conv_w = (const float*)d_in[1];
    const float* bn_g   = (const float*)d_in[2];
    const float* bn_b   = (const float*)d_in[3];
    const float* q_w    = (const float*)d_in[4];
    const float* q_b    = (const float*)d_in[5];
    const float* k_w    = (const float*)d_in[6];
    const float* k_b    = (const float*)d_in[7];
    const float* v_w    = (const float*)d_in[8];
    const float* v_b    = (const float*)d_in[9];
    const float* gca    = (const float*)d_in[10];
    const float* gpa    = (const float*)d_in[11];
    float* out = (float*)d_out;

    float* ws = (float*)d_ws;
    // dead-by-pam region (aliased by pamP, 4 slices = 4,194,304 f):
    float* convY  = ws;                                      // 2,097,152 f
    unsigned short* xTp = (unsigned short*)(ws + 2097152);   // 2,230,272 f
    // alive-through-pam region:
    float* ep     = ws + 4327424;                            // 4,194,304 f (64 slices)
    unsigned short* Wb2  = (unsigned short*)(ws + 8521728);  // 147,456 f
    unsigned short* Wqkv = (unsigned short*)(ws + 8669184);  // 10,240 f
    float* statsS  = ws + 8679424;                           // 128
    float* statsQ  = ws + 8679552;                           // 128
    float* biasAll = ws + 8679680;                           // 192 (pad)
    unsigned short* attnB = (unsigned short*)(ws + 8679872);  // 32,768 f
    unsigned short* qT    = (unsigned short*)(ws + 8712640);  // 131,072 f
    unsigned short* kT    = (unsigned short*)(ws + 8843712);  // 131,072 f
    unsigned short* vB    = (unsigned short*)(ws + 8974784);  // 1,048,576 f
    unsigned short* featB = (unsigned short*)(ws + 10023360); // 1,048,576 f
    unsigned short* fT    = (unsigned short*)(ws + 11071936); // 1,048,576 f -> 12,120,512 f
    // convP (BN partials, 256 slots x 512 blocks = 131,072 f) reuses the
    // ep region (dead until camqkv; conv -> reduce -> bn all precede it).
    float* convP = ws + 4327424;
    // pamP bf16[4][4][128][4096] = 8,388,608 sh = 4,194,304 f, aliases
    // [0, 4,327,424) = convY+xTp (dead before pam; ep stays clear).
    unsigned short* pamP  = (unsigned short*)ws;

    prep_all_kernel<<<2257, 256, 0, stream>>>(x, conv_w, q_w, q_b, k_w, k_b,
                                              v_w, v_b, xTp, Wb2, Wqkv, biasAll,
                                              statsS, statsQ);
    conv_mfma_kernel<<<512, 256, 0, stream>>>(xTp, Wb2, convY, convP);
    stats_reduce_kernel<<<256, 64, 0, stream>>>(convP, statsS, statsQ);
    bn_apply_kernel<<<dim3(2, 64, 4), 256, 0, stream>>>(convY, statsS, statsQ,
                                                        bn_g, bn_b, featB, fT);
    camqkv_kernel<<<512, 256, 0, stream>>>(featB, ep, Wqkv, biasAll, fT, qT, kT, vB);
    pam_attn_kernel<<<768, 256, 0, stream>>>(qT, kT, vB, pamP, ep, attnB);
    combine_kernel<<<dim3(64, 4), 256, 0, stream>>>(attnB, fT, featB, pamP, gca, gpa, out);
}

// Round 16
// 170.755 us; speedup vs baseline: 1.0251x; 1.0251x over previous
//
#include <hip/hip_runtime.h>
#include <math.h>

// Problem constants
#define BATCH 4
#define CIN   256
#define CCH   128      // Cout
#define HW    4096     // 64*64
#define CQK   16

using short8   = __attribute__((ext_vector_type(8))) short;
using floatx4  = __attribute__((ext_vector_type(4))) float;
using floatx16 = __attribute__((ext_vector_type(16))) float;
using uint4v   = __attribute__((ext_vector_type(4))) unsigned int;

// tanh via raw intrinsics: 1 v_mul + v_exp + v_add + v_rcp + v_fma.
// Saturates correctly: x->+inf => exp2->inf => rcp->0 => 1; x->-inf => -1.
__device__ __forceinline__ float fast_tanh(float x) {
    float e = __builtin_amdgcn_exp2f(x * 2.8853900817779268f);  // e^{2x}
    float r = __builtin_amdgcn_rcpf(e + 1.0f);
    return __builtin_fmaf(-2.0f, r, 1.0f);
}

__device__ __forceinline__ unsigned short f2bf(float f) {
    unsigned u = __float_as_uint(f);
    u += 0x7fff + ((u >> 16) & 1);   // RNE
    return (unsigned short)(u >> 16);
}

__device__ __forceinline__ float bf2f(unsigned short u) {
    return __uint_as_float(((unsigned)u) << 16);
}

// C/D row map for mfma_f32_32x32x16: row = (r&3) + 8*(r>>2) + 4*hi, col = lane&31
#define ROWMAP(r, hi) (((r) & 3) + (((r) >> 2) << 3) + ((hi) << 2))

#define XTP_ROW   (66 * 256)          // shorts per padded row
#define XTP_BATCH (66 * 66 * 256)     // shorts per batch

// ---------------------------------------------------------------------------
// 1) prep_all: [0,1024) x-transpose+halo; [1024,2176) conv weights;
//    [2176,2256) qkv weights; [2256] zero stats. grid 2257, block 256.
// ---------------------------------------------------------------------------
__global__ __launch_bounds__(256) void prep_all_kernel(
        const float* __restrict__ x, const float* __restrict__ w,
        const float* __restrict__ qw, const float* __restrict__ qb,
        const float* __restrict__ kw, const float* __restrict__ kb,
        const float* __restrict__ vw, const float* __restrict__ vb,
        unsigned short* __restrict__ xTp, unsigned short* __restrict__ Wb2,
        unsigned short* __restrict__ Wqkv, float* __restrict__ biasAll,
        float* __restrict__ statsS, float* __restrict__ statsQ) {
    const int bx = blockIdx.x, tid = threadIdx.x;
    if (bx < 1024) {
        __shared__ unsigned short lds[64][72];
        const int ci0 = (bx & 3) << 6, yr = (bx >> 2) & 63, b = bx >> 8;
        const int cir = tid >> 2, xc = tid & 3;
        const float* xp = x + (((b << 8) + ci0 + cir) << 12) + (yr << 6) + xc * 16;
#pragma unroll
        for (int j = 0; j < 4; ++j) {
            float4 v = *(const float4*)(xp + j * 4);
            int xi = xc * 16 + j * 4;
            lds[xi + 0][cir] = f2bf(v.x);
            lds[xi + 1][cir] = f2bf(v.y);
            lds[xi + 2][cir] = f2bf(v.z);
            lds[xi + 3][cir] = f2bf(v.w);
        }
        const short8 z8 = (short8){0,0,0,0,0,0,0,0};
        if (tid < 16) {
            int col = (tid >> 3) ? 65 : 0;
            int part = tid & 7;
            *(short8*)(xTp + b * XTP_BATCH + (yr + 1) * XTP_ROW + col * 256 +
                       ci0 + part * 8) = z8;
        }
        if (yr == 0 || yr == 63) {
            int row = (yr == 0) ? 0 : 65;
            for (int e = tid; e < 528; e += 256) {
                int xi = e >> 3, part = e & 7;
                *(short8*)(xTp + b * XTP_BATCH + row * XTP_ROW + xi * 256 +
                           ci0 + part * 8) = z8;
            }
        }
        __syncthreads();
        const int xr = tid >> 2, part = tid & 3;
        unsigned short* dst = xTp + b * XTP_BATCH + (yr + 1) * XTP_ROW +
                              (xr + 1) * 256 + ci0 + part * 16;
        *(short8*)(dst + 0) = *(const short8*)&lds[xr][part * 16 + 0];
        *(short8*)(dst + 8) = *(const short8*)&lds[xr][part * 16 + 8];
    } else if (bx < 2176) {
        int o = (bx - 1024) * 256 + tid;                 // < 294912
        int s   = o & 31;
        int co  = (o >> 5) & 127;
        int cc  = (o >> 12) & 7;
        int tap = o >> 15;
        int ci  = (cc << 5) + s;
        Wb2[o] = f2bf(w[co * 2304 + ci * 9 + tap]);
    } else if (bx < 2256) {
        int idx = (bx - 2176) * 256 + tid;               // < 20480
        int o = idx >> 7, c = idx & 127;
        float wv = (o < 16) ? qw[(o << 7) + c]
                 : (o < 32) ? kw[((o - 16) << 7) + c]
                            : vw[((o - 32) << 7) + c];
        Wqkv[idx] = f2bf(wv);
        if (idx < 160)
            biasAll[idx] = (idx < 16) ? qb[idx] : (idx < 32) ? kb[idx - 16] : vb[idx - 32];
    } else {
        if (tid < 128) { statsS[tid] = 0.f; statsQ[tid] = 0.f; }
    }
}

// ---------------------------------------------------------------------------
// 2) Conv implicit GEMM, m97-style (atomic-free BN partials to convP;
//    fixed the 72us same-address atomic-serialization pin in round 5).
// ---------------------------------------------------------------------------
#define LOADBAND(R, KY)                                                        \
    {                                                                          \
        const unsigned short* g_ = bandbase + (KY) * XTP_ROW;                  \
        _Pragma("unroll")                                                      \
        for (int j = 0; j < 4; ++j)                                            \
            R[j] = *(const short8*)(g_ + ((tid + j * 256) << 3));              \
        if (tid < 64) R[4] = *(const short8*)(g_ + ((1024 + tid) << 3));       \
    }

#define WRITEBAND(R, BUF)                                                      \
    {                                                                          \
        char* p_ = (char*)&Bl[BUF][0];                                         \
        _Pragma("unroll")                                                      \
        for (int j = 0; j < 4; ++j) {                                          \
            int bb_ = (tid + j * 256) << 4;                                    \
            *(short8*)(p_ + (bb_ ^ (((bb_ >> 9) & 7) << 4))) = R[j];           \
        }                                                                      \
        if (tid < 64) {                                                        \
            int bb_ = (1024 + tid) << 4;                                       \
            *(short8*)(p_ + (bb_ ^ (((bb_ >> 9) & 7) << 4))) = R[4];           \
        }                                                                      \
    }

#define LOADA(P, TAP)                                                          \
    {                                                                          \
        const unsigned short* ar_ = Wb2 + ((TAP) << 15) + (aco0 << 5) + (quad << 3); \
        _Pragma("unroll")                                                      \
        for (int cc = 0; cc < 8; ++cc) {                                       \
            P[2 * cc]     = *(const short8*)(ar_ + (cc << 12));                \
            P[2 * cc + 1] = *(const short8*)(ar_ + (cc << 12) + 512);          \
        }                                                                      \
    }

#define CONVSTEP(BUF, KX, PC, PN, TAPN, PREF)                                  \
    {                                                                          \
        const char* bp_ = (const char*)&Bl[BUF][0];                            \
        const int pl0_ = l15 + (KX);                                           \
        const int sw_ = (pl0_ & 7) << 4;                                       \
        const int b0_ = (pl0_ << 9) + (quad << 4);                             \
        const int b1_ = b0_ + (16 << 9);                                       \
        const unsigned short* arn_ = Wb2 + ((TAPN) << 15) + (aco0 << 5) + (quad << 3); \
        _Pragma("unroll")                                                      \
        for (int cc = 0; cc < 8; ++cc) {                                       \
            if (PREF) {                                                        \
                PN[2 * cc]     = *(const short8*)(arn_ + (cc << 12));          \
                PN[2 * cc + 1] = *(const short8*)(arn_ + (cc << 12) + 512);    \
            }                                                                  \
            short8 bf0 = *(const short8*)(bp_ + ((b0_ + (cc << 6)) ^ sw_));    \
            short8 bf1 = *(const short8*)(bp_ + ((b1_ + (cc << 6)) ^ sw_));    \
            acc00 = __builtin_amdgcn_mfma_f32_16x16x32_bf16(PC[2 * cc], bf0, acc00, 0, 0, 0); \
            acc01 = __builtin_amdgcn_mfma_f32_16x16x32_bf16(PC[2 * cc], bf1, acc01, 0, 0, 0); \
            acc10 = __builtin_amdgcn_mfma_f32_16x16x32_bf16(PC[2 * cc + 1], bf0, acc10, 0, 0, 0); \
            acc11 = __builtin_amdgcn_mfma_f32_16x16x32_bf16(PC[2 * cc + 1], bf1, acc11, 0, 0, 0); \
        }                                                                      \
    }

__global__ __launch_bounds__(256, 2) void conv_mfma_kernel(
        const unsigned short* __restrict__ xTp, const unsigned short* __restrict__ Wb2,
        float* __restrict__ y, float* __restrict__ convP) {
    const int tid = threadIdx.x;
    const int w = tid >> 6, lane = tid & 63, l15 = lane & 15, quad = lane >> 4;
    const int idx = blockIdx.x;
    const int xcd = idx & 7, rr = idx >> 3;
    const int yl = rr & 7, ph = (rr >> 3) & 1, b = rr >> 4;
    const int yr = (xcd << 3) + yl;
    const int cobase = w << 5;
    const int px0 = ph << 5;
    const int aco0 = cobase + l15;

    __shared__ __align__(16) unsigned short Bl[2][8704];

    const unsigned short* bandbase = xTp + b * XTP_BATCH + yr * XTP_ROW + (px0 << 8);

    floatx4 acc00 = (floatx4){0.f, 0.f, 0.f, 0.f};
    floatx4 acc01 = (floatx4){0.f, 0.f, 0.f, 0.f};
    floatx4 acc10 = (floatx4){0.f, 0.f, 0.f, 0.f};
    floatx4 acc11 = (floatx4){0.f, 0.f, 0.f, 0.f};

    short8 r0[5], r1[5], r2[5];
    short8 AbA[16], AbB[16];

    LOADBAND(r0, 0);
    WRITEBAND(r0, 0);
    LOADBAND(r1, 1);
    LOADA(AbA, 0);
    __syncthreads();

    WRITEBAND(r1, 1);
    LOADBAND(r2, 2);
    CONVSTEP(0, 0, AbA, AbB, 1, 1)
    CONVSTEP(0, 1, AbB, AbA, 2, 1)
    CONVSTEP(0, 2, AbA, AbB, 3, 1)
    __syncthreads();

    WRITEBAND(r2, 0);
    CONVSTEP(1, 0, AbB, AbA, 4, 1)
    CONVSTEP(1, 1, AbA, AbB, 5, 1)
    CONVSTEP(1, 2, AbB, AbA, 6, 1)
    __syncthreads();

    CONVSTEP(0, 0, AbA, AbB, 7, 1)
    CONVSTEP(0, 1, AbB, AbA, 8, 1)
    CONVSTEP(0, 2, AbA, AbB, 0, 0)

#pragma unroll
    for (int ns = 0; ns < 2; ++ns) {
        int px = px0 + (ns << 4) + l15;
        floatx4 a0 = ns ? acc01 : acc00;
        floatx4 a1 = ns ? acc11 : acc10;
#pragma unroll
        for (int r = 0; r < 4; ++r) {
            int co0 = cobase + (quad << 2) + r;
            y[(((b << 7) + co0) << 12) + (yr << 6) + px] = a0[r];
            y[(((b << 7) + co0 + 16) << 12) + (yr << 6) + px] = a1[r];
        }
    }

#pragma unroll
    for (int ms = 0; ms < 2; ++ms) {
        floatx4 aa = ms ? acc10 : acc00;
        floatx4 ab = ms ? acc11 : acc01;
#pragma unroll
        for (int r = 0; r < 4; ++r) {
            float s = aa[r] + ab[r];
            float q = aa[r] * aa[r] + ab[r] * ab[r];
#pragma unroll
            for (int off = 1; off < 16; off <<= 1) {
                s += __shfl_xor(s, off);
                q += __shfl_xor(q, off);
            }
            if (l15 == 0) {
                int co = cobase + ms * 16 + (quad << 2) + r;
                convP[(co << 9) + idx] = s;
                convP[((128 + co) << 9) + idx] = q;
            }
        }
    }
}

// ---------------------------------------------------------------------------
// 2b) stats_reduce: sum the 512 per-block partials per slot.
//     grid 256 (slot = co for S, 128+co for Q), block 64.
// ---------------------------------------------------------------------------
__global__ __launch_bounds__(64) void stats_reduce_kernel(
        const float* __restrict__ convP, float* __restrict__ statsS,
        float* __restrict__ statsQ) {
    const int s = blockIdx.x, t = threadIdx.x;
    const float* p = convP + (s << 9);
    float v = 0.f;
#pragma unroll
    for (int j = 0; j < 8; ++j) v += p[t + (j << 6)];
#pragma unroll
    for (int off = 32; off; off >>= 1) v += __shfl_xor(v, off);
    if (t == 0) {
        if (s < 128) statsS[s] = v;
        else         statsQ[s - 128] = v;
    }
}

// ---------------------------------------------------------------------------
// 3) BN apply + ReLU (scale computed inline from sums) -> featB + fT.
// grid(2, 64, 4), block 256
// ---------------------------------------------------------------------------
__global__ __launch_bounds__(256) void bn_apply_kernel(
        const float* __restrict__ y, const float* __restrict__ statsS,
        const float* __restrict__ statsQ, const float* __restrict__ gamma,
        const float* __restrict__ beta, unsigned short* __restrict__ featB,
        unsigned short* __restrict__ fT) {
    __shared__ unsigned short lds[64][72];
    const int tid = threadIdx.x;
    const int c0 = blockIdx.x * 64, n0 = blockIdx.y * 64, b = blockIdx.z;
    const int cir = tid >> 2, xc = tid & 3;
    const int c = c0 + cir;
    const float S = statsS[c], Q = statsQ[c];
    const float mean = S * (1.f / 16384.f);
    const float var  = Q * (1.f / 16384.f) - mean * mean;
    const float rstd = rsqrtf(var + 1e-5f);
    const float sc = gamma[c] * rstd;
    const float sh = beta[c] - mean * sc;
    const float* yp = y + (((b << 7) + c) << 12) + n0 + xc * 16;
    unsigned short* fp = featB + (((b << 7) + c) << 12) + n0 + xc * 16;
#pragma unroll
    for (int j = 0; j < 4; ++j) {
        float4 v = *(const float4*)(yp + j * 4);
        ushort4 o;
        o.x = f2bf(fmaxf(fmaf(v.x, sc, sh), 0.f));
        o.y = f2bf(fmaxf(fmaf(v.y, sc, sh), 0.f));
        o.z = f2bf(fmaxf(fmaf(v.z, sc, sh), 0.f));
        o.w = f2bf(fmaxf(fmaf(v.w, sc, sh), 0.f));
        *(ushort4*)(fp + j * 4) = o;
        int ni = xc * 16 + j * 4;
        lds[ni + 0][cir] = o.x;
        lds[ni + 1][cir] = o.y;
        lds[ni + 2][cir] = o.z;
        lds[ni + 3][cir] = o.w;
    }
    __syncthreads();
    const int nr = tid >> 2, part = tid & 3;
    unsigned short* dst = fT + (((b << 12) + n0 + nr) << 7) + c0 + part * 16;
    *(short8*)(dst + 0) = *(const short8*)&lds[nr][part * 16 + 0];
    *(short8*)(dst + 8) = *(const short8*)&lds[nr][part * 16 + 8];
}

// ---------------------------------------------------------------------------
// 4) Fused cam_energy (blocks [0,256)) + qkv (blocks [256,512)). grid 512.
// ---------------------------------------------------------------------------
__global__ __launch_bounds__(256) void camqkv_kernel(
        const unsigned short* __restrict__ featB, float* __restrict__ ep,
        const unsigned short* __restrict__ Wqkv, const float* __restrict__ biasAll,
        const unsigned short* __restrict__ fT,
        unsigned short* __restrict__ qT, unsigned short* __restrict__ kT,
        unsigned short* __restrict__ vB) {
    const int bx = blockIdx.x, tid = threadIdx.x;
    const int l31 = tid & 31, hi = (tid >> 5) & 1;
    if (bx < 256) {
        // cam_energy: split-K 64, kc = bx&63, b = bx>>6
        const int kc = bx & 63, b = bx >> 6, wv = tid >> 6;
        floatx16 acc[4];
#pragma unroll
        for (int t = 0; t < 4; ++t)
#pragma unroll
            for (int r = 0; r < 16; ++r) acc[t][r] = 0.f;
        for (int s = 0; s < 4; ++s) {
            const int k0 = (kc << 6) + (s << 4) + (hi << 3);
            short8 fr = *(const short8*)&featB[(((b << 7) + (wv << 5) + l31) << 12) + k0];
            short8 fc0 = *(const short8*)&featB[(((b << 7) +  0 + l31) << 12) + k0];
            short8 fc1 = *(const short8*)&featB[(((b << 7) + 32 + l31) << 12) + k0];
            short8 fc2 = *(const short8*)&featB[(((b << 7) + 64 + l31) << 12) + k0];
            short8 fc3 = *(const short8*)&featB[(((b << 7) + 96 + l31) << 12) + k0];
            acc[0] = __builtin_amdgcn_mfma_f32_32x32x16_bf16(fr, fc0, acc[0], 0, 0, 0);
            acc[1] = __builtin_amdgcn_mfma_f32_32x32x16_bf16(fr, fc1, acc[1], 0, 0, 0);
            acc[2] = __builtin_amdgcn_mfma_f32_32x32x16_bf16(fr, fc2, acc[2], 0, 0, 0);
            acc[3] = __builtin_amdgcn_mfma_f32_32x32x16_bf16(fr, fc3, acc[3], 0, 0, 0);
        }
#pragma unroll
        for (int t = 0; t < 4; ++t)
#pragma unroll
            for (int r = 0; r < 16; ++r) {
                int c = ((tid >> 6) << 5) + ROWMAP(r, hi);
                int d = (t << 5) + l31;
                ep[(((kc << 2) + b) << 14) + (c << 7) + d] = acc[t][r];
            }
    } else {
        // qkv: bi = bx-256; ntile = bi&63, b = bi>>6
        const int bi = bx - 256, b = bi >> 6, w = tid >> 6;
        const int n0 = ((bi & 63) << 6) + ((w >> 1) << 5);
        const int tstart = (w & 1) ? 3 : 0;
        const int tcnt   = (w & 1) ? 2 : 3;
        floatx16 acc[3];
#pragma unroll
        for (int t = 0; t < 3; ++t)
#pragma unroll
            for (int r = 0; r < 16; ++r) acc[t][r] = 0.f;
        for (int s = 0; s < 8; ++s) {
            const int k0 = (s << 4) + (hi << 3);
            short8 bf = *(const short8*)&fT[(((b << 12) + n0 + l31) << 7) + k0];
#pragma unroll
            for (int ti = 0; ti < 3; ++ti) {
                if (ti < tcnt) {
                    short8 aw = *(const short8*)&Wqkv[((((tstart + ti) << 5) + l31) << 7) + k0];
                    acc[ti] = __builtin_amdgcn_mfma_f32_32x32x16_bf16(aw, bf, acc[ti], 0, 0, 0);
                }
            }
        }
        const int n = n0 + l31;
#pragma unroll
        for (int ti = 0; ti < 3; ++ti) {
            if (ti >= tcnt) continue;
            const int t = tstart + ti;
#pragma unroll
            for (int r = 0; r < 16; ++r) {
                int o = (t << 5) + ROWMAP(r, hi);
                float val = acc[ti][r] + biasAll[o];
                if (t == 0) {
                    if (o < 16) qT[(((b << 12) + n) << 4) + o] = f2bf(val);
                    else        kT[(((b << 12) + n) << 4) + o - 16] = f2bf(val);
                } else if (o >= 32) {
                    vB[(((b << 7) + o - 32) << 12) + n] = f2bf(val);
                }
            }
        }
    }
}

// ---------------------------------------------------------------------------
// 5) Fused pam (blocks [0,512)) + cam_attn (blocks [512,768)). grid 768.
//    FINAL (round-14 configuration, best measured 172.8us): round-5
//    structure -- early V-loads (8 ds_read_b128 issued before any
//    dependent use), stride 40 (80B rows, 16B-aligned -> single
//    ds_read_b128 per load), 4-way n-split, double-buffered V tiles --
//    plus the r14-validated permlane half-swap: 4 v_permlane32_swap_b32
//    (VALU) replace 8 ds_bpermute + 16 cndmask on the serial chain.
// ---------------------------------------------------------------------------
#define PAM_STEP(LB, NC)                                                          \
    {                                                                             \
        const unsigned short* lb_ = (LB);                                         \
        const int na_ = nbase + ((NC) << 5);                                      \
        short8 avl0 = *(const short8*)(lb_ + ( l31       * 40) + hi * 8);         \
        short8 avh0 = *(const short8*)(lb_ + ( l31       * 40) + 16 + hi * 8);    \
        short8 avl1 = *(const short8*)(lb_ + ((32 + l31) * 40) + hi * 8);         \
        short8 avh1 = *(const short8*)(lb_ + ((32 + l31) * 40) + 16 + hi * 8);    \
        short8 avl2 = *(const short8*)(lb_ + ((64 + l31) * 40) + hi * 8);         \
        short8 avh2 = *(const short8*)(lb_ + ((64 + l31) * 40) + 16 + hi * 8);    \
        short8 avl3 = *(const short8*)(lb_ + ((96 + l31) * 40) + hi * 8);         \
        short8 avh3 = *(const short8*)(lb_ + ((96 + l31) * 40) + 16 + hi * 8);    \
        floatx16 s_ = __builtin_amdgcn_mfma_f32_32x32x16_bf16(ak, bq, zero16, 0, 0, 0); \
        if ((NC) < 31)                                                            \
            ak = *(const short8*)&kT[(((b << 12) + na_ + 32 + l31) << 4) + hi * 8]; \
        unsigned p_[8];                                                           \
        _Pragma("unroll")                                                         \
        for (int i = 0; i < 8; ++i) {                                             \
            float t0 = fast_tanh(s_[2 * i]);                                      \
            float t1 = fast_tanh(s_[2 * i + 1]);                                  \
            p_[i] = (__float_as_uint(t1) & 0xFFFF0000u) | (__float_as_uint(t0) >> 16); \
        }                                                                         \
        unsigned q0 = p_[0], q1 = p_[1], q2 = p_[2], q3 = p_[3];                  \
        unsigned q4 = p_[4], q5 = p_[5], q6 = p_[6], q7 = p_[7];                  \
        asm("v_permlane32_swap_b32 %0, %1" : "+v"(q0), "+v"(q2));                 \
        asm("v_permlane32_swap_b32 %0, %1" : "+v"(q1), "+v"(q3));                 \
        asm("v_permlane32_swap_b32 %0, %1" : "+v"(q4), "+v"(q6));                 \
        asm("v_permlane32_swap_b32 %0, %1" : "+v"(q5), "+v"(q7));                 \
        uint4v b1u, b2u;                                                          \
        b1u[0] = q0; b1u[1] = q1; b1u[2] = q2; b1u[3] = q3;                       \
        b2u[0] = q4; b2u[1] = q5; b2u[2] = q6; b2u[3] = q7;                       \
        short8 B1 = __builtin_bit_cast(short8, b1u);                              \
        short8 B2 = __builtin_bit_cast(short8, b2u);                              \
        __builtin_amdgcn_s_setprio(1);                                            \
        acc[0] = __builtin_amdgcn_mfma_f32_32x32x16_bf16(avl0, B1, acc[0], 0, 0, 0); \
        acc[0] = __builtin_amdgcn_mfma_f32_32x32x16_bf16(avh0, B2, acc[0], 0, 0, 0); \
        acc[1] = __builtin_amdgcn_mfma_f32_32x32x16_bf16(avl1, B1, acc[1], 0, 0, 0); \
        acc[1] = __builtin_amdgcn_mfma_f32_32x32x16_bf16(avh1, B2, acc[1], 0, 0, 0); \
        acc[2] = __builtin_amdgcn_mfma_f32_32x32x16_bf16(avl2, B1, acc[2], 0, 0, 0); \
        acc[2] = __builtin_amdgcn_mfma_f32_32x32x16_bf16(avh2, B2, acc[2], 0, 0, 0); \
        acc[3] = __builtin_amdgcn_mfma_f32_32x32x16_bf16(avl3, B1, acc[3], 0, 0, 0); \
        acc[3] = __builtin_amdgcn_mfma_f32_32x32x16_bf16(avh3, B2, acc[3], 0, 0, 0); \
        __builtin_amdgcn_s_setprio(0);                                            \
    }

__global__ __launch_bounds__(256) void pam_attn_kernel(
        const unsigned short* __restrict__ qT, const unsigned short* __restrict__ kT,
        const unsigned short* __restrict__ vB, unsigned short* __restrict__ pamP,
        const float* __restrict__ ep, unsigned short* __restrict__ attnB) {
    const int bx = blockIdx.x, tid = threadIdx.x;
    if (bx < 512) {
        const int nh = bx & 3, b = bx >> 7;
        const int w = tid >> 6, lane = tid & 63, l31 = lane & 31, hi = lane >> 5;
        const int m0 = (((bx >> 2) & 31) << 7) + (w << 5);

        // 2 buffers x 128 rows x 40 shorts (32 data + 8 pad) = 20,480 B
        __shared__ __align__(16) unsigned short vtile[2][5120];

        short8 bq = *(const short8*)&qT[(((b << 12) + m0 + l31) << 4) + hi * 8];

        floatx16 acc[4], zero16;
#pragma unroll
        for (int r = 0; r < 16; ++r) {
            acc[0][r] = 0.f; acc[1][r] = 0.f; acc[2][r] = 0.f; acc[3][r] = 0.f;
            zero16[r] = 0.f;
        }

        const int nbase = nh << 10;

        // staging mapping: thread -> (row 0..127, 32B half)
        const int srow = tid >> 1, shalf = tid & 1;
        const unsigned short* vg = vB + (((b << 7) + srow) << 12) + nbase + shalf * 16;
        unsigned short* sw0 = &vtile[0][srow * 40 + shalf * 16];
        unsigned short* sw1 = &vtile[1][srow * 40 + shalf * 16];

        short8 ak = *(const short8*)&kT[(((b << 12) + nbase + l31) << 4) + hi * 8];

        // prologue: fetch tiles 0 and 1; write tile 0 into buf0
        short8 gA0 = *(const short8*)(vg + 0);
        short8 gA1 = *(const short8*)(vg + 8);
        short8 gB0 = *(const short8*)(vg + 32);
        short8 gB1 = *(const short8*)(vg + 40);
        *(short8*)(sw0 + 0) = gA0;
        *(short8*)(sw0 + 8) = gA1;

        for (int t = 0; t < 16; ++t) {
            const int e = t << 1;
            // ---- phase A: consume tile e from buf0 ----
            __syncthreads();
            *(short8*)(sw1 + 0) = gB0;          // tile e+1 -> buf1
            *(short8*)(sw1 + 8) = gB1;
            if (t < 15) {                        // fetch tile e+2
                gA0 = *(const short8*)(vg + (e + 2) * 32);
                gA1 = *(const short8*)(vg + (e + 2) * 32 + 8);
            }
            PAM_STEP(&vtile[0][0], e);
            // ---- phase B: consume tile e+1 from buf1 ----
            __syncthreads();
            if (t < 15) {
                *(short8*)(sw0 + 0) = gA0;      // tile e+2 -> buf0
                *(short8*)(sw0 + 8) = gA1;
                gB0 = *(const short8*)(vg + (e + 3) * 32);   // fetch tile e+3
                gB1 = *(const short8*)(vg + (e + 3) * 32 + 8);
            }
            PAM_STEP(&vtile[1][0], e + 1);
        }

        const int pbase = (((nh << 2) + b) << 19) + m0 + l31;
#pragma unroll
        for (int ct = 0; ct < 4; ++ct)
#pragma unroll
            for (int r = 0; r < 16; ++r) {
                int c = (ct << 5) + ROWMAP(r, hi);
                pamP[pbase + (c << 12)] = f2bf(acc[ct][r]);
            }
    } else {
        // cam_attn: bi = bx-512 (0..255): b = bi>>6, 2 rows per block
        const int bi = bx - 512, b = bi >> 6;
        const int half = tid >> 7, t = tid & 127;
        const int c = ((bi & 63) << 1) + half;
        float v = 0.f;
#pragma unroll 8
        for (int s = 0; s < 64; ++s)
            v += ep[(((s << 2) + b) << 14) + (c << 7) + t];
        float m = v;
        for (int off = 32; off; off >>= 1) m = fmaxf(m, __shfl_down(m, off));
        __shared__ float mx[4];
        if ((tid & 63) == 0) mx[tid >> 6] = m;
        __syncthreads();
        float M = fmaxf(mx[half << 1], mx[(half << 1) + 1]);
        attnB[(b << 14) + (c << 7) + t] = f2bf(fast_tanh(M - v));
    }
}

// ---------------------------------------------------------------------------
// 6) Combine: out = 3*feat + g_ca*(attn @ f) + g_pa*(sum_4 pamP).
// grid(64, 4), block 256.
// ---------------------------------------------------------------------------
__global__ __launch_bounds__(256) void combine_kernel(
        const unsigned short* __restrict__ attnB, const unsigned short* __restrict__ fT,
        const unsigned short* __restrict__ featB, const unsigned short* __restrict__ pamP,
        const float* __restrict__ gca, const float* __restrict__ gpa,
        float* __restrict__ out) {
    const int b = blockIdx.y, tid = threadIdx.x;
    const int w = tid >> 6, l31 = tid & 31, hi = (tid >> 5) & 1;
    const int m0 = (blockIdx.x << 6) + ((w >> 1) << 5);
    const int ct0 = (w & 1) << 1;
    floatx16 acc[2];
#pragma unroll
    for (int t = 0; t < 2; ++t)
#pragma unroll
        for (int r = 0; r < 16; ++r) acc[t][r] = 0.f;

    for (int s = 0; s < 8; ++s) {
        const int k0 = (s << 4) + (hi << 3);
        short8 bf = *(const short8*)&fT[(((b << 12) + m0 + l31) << 7) + k0];
        short8 a0 = *(const short8*)&attnB[(b << 14) + ((((ct0 + 0) << 5) + l31) << 7) + k0];
        short8 a1 = *(const short8*)&attnB[(b << 14) + ((((ct0 + 1) << 5) + l31) << 7) + k0];
        acc[0] = __builtin_amdgcn_mfma_f32_32x32x16_bf16(a0, bf, acc[0], 0, 0, 0);
        acc[1] = __builtin_amdgcn_mfma_f32_32x32x16_bf16(a1, bf, acc[1], 0, 0, 0);
    }
    const float gc = gca[0], gp = gpa[0];
    const int m = m0 + l31;
#pragma unroll
    for (int t = 0; t < 2; ++t)
#pragma unroll
        for (int r = 0; r < 16; ++r) {
            int c = ((ct0 + t) << 5) + ROWMAP(r, hi);
            int ci = (c << 12) + m;
            float p = bf2f(pamP[((0 * 4 + b) << 19) + ci]) +
                      bf2f(pamP[((1 * 4 + b) << 19) + ci]) +
                      bf2f(pamP[((2 * 4 + b) << 19) + ci]) +
                      bf2f(pamP[((3 * 4 + b) << 19) + ci]);
            float fb = bf2f(featB[(((b << 7) + c) << 12) + m]);
            out[(((b << 7) + c) << 12) + m] = 3.f * fb + gc * acc[t][r] + gp * p;
        }
}

// ---------------------------------------------------------------------------
extern "C" void kernel_launch(void* const* d_in, const int* in_sizes, int n_in,
                              void* d_out, int out_size, void* d_ws, size_t ws_size,
                              hipStream_t stream) {
    const float* x      = (const float*)d_in[0];
    const float* conv_w = (const float*)d_in[1];
    const float* bn_g   = (const float*)d_in[2];
    const float* bn_b   = (const float*)d_in[3];
    const float* q_w    = (const float*)d_in[4];
    const float* q_b    = (const float*)d_in[5];
    const float* k_w    = (const float*)d_in[6];
    const float* k_b    = (const float*)d_in[7];
    const float* v_w    = (const float*)d_in[8];
    const float* v_b    = (const float*)d_in[9];
    const float* gca    = (const float*)d_in[10];
    const float* gpa    = (const float*)d_in[11];
    float* out = (float*)d_out;

    float* ws = (float*)d_ws;
    // dead-by-pam region (aliased by pamP, 4 slices = 4,194,304 f):
    float* convY  = ws;                                      // 2,097,152 f
    unsigned short* xTp = (unsigned short*)(ws + 2097152);   // 2,230,272 f
    // alive-through-pam region:
    float* ep     = ws + 4327424;                            // 4,194,304 f (64 slices)
    unsigned short* Wb2  = (unsigned short*)(ws + 8521728);  // 147,456 f
    unsigned short* Wqkv = (unsigned short*)(ws + 8669184);  // 10,240 f
    float* statsS  = ws + 8679424;                           // 128
    float* statsQ  = ws + 8679552;                           // 128
    float* biasAll = ws + 8679680;                           // 192 (pad)
    unsigned short* attnB = (unsigned short*)(ws + 8679872);  // 32,768 f
    unsigned short* qT    = (unsigned short*)(ws + 8712640);  // 131,072 f
    unsigned short* kT    = (unsigned short*)(ws + 8843712);  // 131,072 f
    unsigned short* vB    = (unsigned short*)(ws + 8974784);  // 1,048,576 f
    unsigned short* featB = (unsigned short*)(ws + 10023360); // 1,048,576 f
    unsigned short* fT    = (unsigned short*)(ws + 11071936); // 1,048,576 f -> 12,120,512 f
    // convP (BN partials, 256 slots x 512 blocks = 131,072 f) reuses the
    // ep region (dead until camqkv; conv -> reduce -> bn all precede it).
    float* convP = ws + 4327424;
    // pamP bf16[4][4][128][4096] = 8,388,608 sh = 4,194,304 f, aliases
    // [0, 4,327,424) = convY+xTp (dead before pam; ep stays clear).
    unsigned short* pamP  = (unsigned short*)ws;

    prep_all_kernel<<<2257, 256, 0, stream>>>(x, conv_w, q_w, q_b, k_w, k_b,
                                              v_w, v_b, xTp, Wb2, Wqkv, biasAll,
                                              statsS, statsQ);
    conv_mfma_kernel<<<512, 256, 0, stream>>>(xTp, Wb2, convY, convP);
    stats_reduce_kernel<<<256, 64, 0, stream>>>(convP, statsS, statsQ);
    bn_apply_kernel<<<dim3(2, 64, 4), 256, 0, stream>>>(convY, statsS, statsQ,
                                                        bn_g, bn_b, featB, fT);
    camqkv_kernel<<<512, 256, 0, stream>>>(featB, ep, Wqkv, biasAll, fT, qT, kT, vB);
    pam_attn_kernel<<<768, 256, 0, stream>>>(qT, kT, vB, pamP, ep, attnB);
    combine_kernel<<<dim3(64, 4), 256, 0, stream>>>(attnB, fT, featB, pamP, gca, gpa, out);
}